// Round 2
// baseline (185.189 us; speedup 1.0000x reference)
//
#include <hip/hip_runtime.h>

// DownSample (fp32 in/out, bf16 MFMA internals), MI355X gfx950
// Shapes: B=128, n_stk=32, n_stk_pnt=32, COOR=32, m=16, k=2
// outputs: sparse_out [128,256,16] | dense_out [128,128,16,16] | coor_out [128,16,32]
//
// R10: revert launch_bounds(256,4) -> plain 256. The ,4 bound crushed VGPRs to
// 64 and spilled (WRITE_SIZE +4.3MB of scratch traffic, k_main 47.5->50us);
// LDS already caps occupancy at 4 blocks/CU so the bound bought nothing.
// Keeps R9 wins: affine BN fold (3 barriers), packed b32 staging writes,
// kt=0 A-frag prefetch. New: sparse staging also packs c-pairs into b32.

typedef unsigned short u16;
typedef unsigned int   u32;
typedef __attribute__((ext_vector_type(8))) short bf16x8;   // 4 VGPRs
typedef __attribute__((ext_vector_type(4))) float f32x4;

#define BN_SCALE 0.9999950000374997f   // 1/sqrt(1+1e-5)

__device__ __forceinline__ float gelu_f(float x){
  return 0.5f*x*(1.0f + erff(x*0.70710678118654752f));
}
__device__ __forceinline__ u16 f2bf(float f){
  u32 x = __float_as_uint(f);
  x += 0x7fffu + ((x>>16)&1u);           // RNE
  return (u16)(x>>16);
}

// ---------------- kernel 1: weight swizzle (blocks 0..831) + FPS (832..959) ----------------
// A-frag layout: afrag[(kt*NT + ot)*64 + lane][j] = W[o = ot*16+(lane&15)][k = kt*32+((lane>>4)&3)*8+j]
__global__ __launch_bounds__(256) void k_prep(
    const float* __restrict__ dn_w, const float* __restrict__ ds_w, const float* __restrict__ sp_w,
    const float* __restrict__ coor,
    u16* __restrict__ wdb, u16* __restrict__ wcb, u16* __restrict__ wsb,
    int* __restrict__ fps_idx, int* __restrict__ nn_idx, float* __restrict__ coor_out)
{
  int blk = blockIdx.x, t = threadIdx.x;
  if (blk < 128){                       // dense MLP W [128o x 256k] -> 8kt x 8ot
    int w = blk*256 + t;
    int j=w&7, lane=(w>>3)&63, tile=w>>9;
    int kt=tile>>3, ot=tile&7;
    int o=ot*16+(lane&15), i=kt*32+((lane>>4)&3)*8+j;
    wdb[w] = f2bf(dn_w[o*256+i]);
  } else if (blk < 320){                // conv W [128o x 384k] -> 12kt x 8ot
    int w = (blk-128)*256 + t;
    int j=w&7, lane=(w>>3)&63, tile=w>>9;
    int kt=tile>>3, ot=tile&7;
    int o=ot*16+(lane&15), k=kt*32+((lane>>4)&3)*8+j;
    wcb[w] = f2bf(ds_w[o*384+k]);
  } else if (blk < 832){                // sparse W [256o x 512k] -> 16kt x 16ot
    int w = (blk-320)*256 + t;
    int j=w&7, lane=(w>>3)&63, tile=w>>9;
    int kt=tile>>4, ot=tile&15;
    int o=ot*16+(lane&15), i=kt*32+((lane>>4)&3)*8+j;
    wsb[w] = f2bf(sp_w[o*512+i]);
  } else {
    // ---- FPS + NN + coor_out for b = blk-832 ----
    int b = blk - 832;
    __shared__ float Xs[32*33];
    __shared__ float D[32*33];
    __shared__ int   s_sel[16];
    for (int i=t;i<1024;i+=256) Xs[(i>>5)*33 + (i&31)] = coor[b*1024+i];
    __syncthreads();
    #pragma unroll
    for (int k2=0;k2<4;k2++){
      int p=t+k2*256, i=p>>5, j=p&31;
      float d=0.f;
      #pragma unroll
      for (int c=0;c<32;c++){ float df=Xs[i*33+c]-Xs[j*33+c]; d+=df*df; }
      D[i*33+j]=d;
    }
    __syncthreads();
    if (t < 64){
      int j = t & 31;
      float dist = 3.0e38f;
      int far = 0;
      #pragma unroll
      for (int it=0; it<16; ++it){
        if (t==0) s_sel[it]=far;
        dist = fminf(dist, D[far*33+j]);
        float v=dist; int idx=j;              // argmax, first-index tie-break
        #pragma unroll
        for (int off=16; off>=1; off>>=1){
          float v2=__shfl_xor(v,off,32); int i2=__shfl_xor(idx,off,32);
          if (v2>v || (v2==v && i2<idx)){ v=v2; idx=i2; }
        }
        far = idx;
      }
      if (t==0){
        #pragma unroll
        for (int it=0;it<16;++it) fps_idx[b*16+it]=s_sel[it];
      }
    }
    __syncthreads();
    {
      int wv=t>>6, j=t&31;
      #pragma unroll
      for (int q=0;q<4;q++){
        int it = wv*4+q, sel = s_sel[it];
        float d = D[sel*33+j];
        if (j==sel) d=3.0e38f;
        float v=d; int idx=j;                 // argmin, first-index tie-break
        #pragma unroll
        for (int off=16; off>=1; off>>=1){
          float v2=__shfl_xor(v,off,32); int i2=__shfl_xor(idx,off,32);
          if (v2<v || (v2==v && i2<idx)){ v=v2; idx=i2; }
        }
        if ((t&63)==0) nn_idx[b*16+it]=idx;
      }
    }
    for (int q=t;q<512;q+=256){
      int mm=q>>5, c=q&31;
      coor_out[b*512+q] = Xs[s_sel[mm]*33 + c];
    }
  }
}

// ---------------- kernel 2: fused sparse (blocks 0..63, 2 b each) + dense (64..1087, 2 m each) ----
__global__ __launch_bounds__(256) void k_main(
    const float* __restrict__ sfea, const u16* __restrict__ wsb,
    const float* __restrict__ sp_b, const float* __restrict__ sp_g, const float* __restrict__ sp_be,
    const float* __restrict__ dfea, const u16* __restrict__ wdb,
    const float* __restrict__ dn_b, const float* __restrict__ dn_g, const float* __restrict__ dn_be,
    const u16* __restrict__ wcb,
    const float* __restrict__ ds_b, const float* __restrict__ ds_g, const float* __restrict__ ds_be,
    const int* __restrict__ fps_idx, const int* __restrict__ nn_idx,
    float* __restrict__ out_sp, float* __restrict__ out_dn)
{
  __shared__ char smem[36352];
  __shared__ int SI[64];
  int blk=blockIdx.x;
  int t=threadIdx.x, lane=t&63, wv=t>>6, quad=lane>>4, col=lane&15;
  if (blk < 64){
    // ======== sparse: b in {2*blk, 2*blk+1}; C = W[256o x 512i] * X[512i x 16m] x2 ========
    int b0 = blk*2;
    u16*   Xb = (u16*)smem;                      // 2 x [16m][520] u16 = 33280 B
    float* P  = (float*)(smem+33280);            // spA | spB : 512 f32 = 2048 B
    if (t<64){
      int bb=t>>5, q=t&31, b=b0+bb;
      SI[t] = ((q<16) ? fps_idx[b*16+q] : nn_idx[b*16+(q-16)]) & 31;
    }
    { float A = sp_g[t]*BN_SCALE; P[t]=A; P[256+t]=fmaf(sp_b[t],A,sp_be[t]); }
    __syncthreads();
    {
      // t = bb(1) x cpair(7) : thread handles channels {2c, 2c+1} of batch bb
      int bb = t>>7, cp = t&127, c = cp*2;
      const float* rowA = sfea + (b0+bb)*8192 + c*32;
      const float* rowB = rowA + 32;
      u16* XbM = Xb + bb*8320;
      #pragma unroll
      for (int m=0;m<16;m++){
        int si = SI[bb*32+m], sn = SI[bb*32+16+m];
        float vcA=rowA[si], vnA=rowA[sn];
        float vcB=rowB[si], vnB=rowB[sn];
        *(u32*)&XbM[m*520 + c]       = (u32)f2bf(vnA-vcA) | ((u32)f2bf(vnB-vcB)<<16);  // diff
        *(u32*)&XbM[m*520 + 256 + c] = (u32)f2bf(vcA)     | ((u32)f2bf(vcB)<<16);      // ctr
      }
    }
    __syncthreads();
    #pragma unroll
    for (int oh=0;oh<2;oh++){
      f32x4 accA[2][2]={}, accB[2][2]={};        // [bb][r]
      #pragma unroll
      for (int kt=0;kt<16;kt++){
        bf16x8 bf0 = *(const bf16x8*)&Xb[        col*520 + kt*32 + quad*8];
        bf16x8 bf1 = *(const bf16x8*)&Xb[8320 +  col*520 + kt*32 + quad*8];
        #pragma unroll
        for (int r=0;r<2;r++){
          bf16x8 afr = *(const bf16x8*)&wsb[((kt*16 + oh*8 + wv + r*4)*64+lane)*8];
          if (kt<8){
            accA[0][r]=__builtin_amdgcn_mfma_f32_16x16x32_bf16(afr,bf0,accA[0][r],0,0,0);
            accA[1][r]=__builtin_amdgcn_mfma_f32_16x16x32_bf16(afr,bf1,accA[1][r],0,0,0);
          } else {
            accB[0][r]=__builtin_amdgcn_mfma_f32_16x16x32_bf16(afr,bf0,accB[0][r],0,0,0);
            accB[1][r]=__builtin_amdgcn_mfma_f32_16x16x32_bf16(afr,bf1,accB[1][r],0,0,0);
          }
        }
      }
      #pragma unroll
      for (int bb=0;bb<2;bb++){
        #pragma unroll
        for (int r=0;r<2;r++){
          #pragma unroll
          for (int reg=0;reg<4;reg++){
            int o = oh*128 + (wv+r*4)*16 + quad*4 + reg;
            float A=P[o], Bv=P[256+o];
            float k1 = accA[bb][r][reg]+accB[bb][r][reg];  // k=1: [diff|ctr]
            float k0 = accB[bb][r][reg];                   // k=0: diff part exactly 0
            float v = fmaxf(gelu_f(fmaf(k1,A,Bv)), gelu_f(fmaf(k0,A,Bv)));
            out_sp[((b0+bb)*256+o)*16 + col] = v;
          }
        }
      }
    }
  } else {
    // ======== dense: d=blk-64; b=((d>>6)<<3)|(d&7); m-pair mp=(d>>3)&7 ========
    int d=blk-64;
    int b = ((d>>6)<<3) | (d&7), m0 = ((d>>3)&7)*2;
    u16* Vb = (u16*)smem;                 // phase 1: 2 x [32p][264] bf16 = 33792 B
    u16* Bc = (u16*)smem;                 // phase 2: 2 x [16x][392] bf16 = 25088 B
    float* Pd = (float*)(smem+33792);     // dnA|dnB|dsA|dsB|a0 : 640 f32 = 2560 B
    if (t < 128){                         // fold BN: out = gelu(acc*A + B)
      float A  = dn_g[t]*BN_SCALE; float Bv = fmaf(dn_b[t], A, dn_be[t]);
      float Ac = ds_g[t]*BN_SCALE; float Cv = fmaf(ds_b[t], Ac, ds_be[t]);
      Pd[t]=A; Pd[128+t]=Bv; Pd[256+t]=Ac; Pd[384+t]=Cv;
      Pd[512+t]=gelu_f(Bv);               // a0 (k=0 diff value)
    }
    int ci0=fps_idx[b*16+m0]&31,   ni0=nn_idx[b*16+m0]&31;
    int ci1=fps_idx[b*16+m0+1]&31, ni1=nn_idx[b*16+m0+1]&31;
    const float* Db = dfea + b*131072;    // dfea[b][c][s][x]: c*1024 + s*32 + x
    #pragma unroll
    for (int it=0; it<4; it++){
      int w = t + it*256;                 // 0..1023 : mi(2) x cpair(64) x xq(8)
      int mi = w>>9, q = w&511;
      int cp = q>>3, xq = q&7;
      int c = cp*2, x = xq*4;
      int ci = mi ? ci1 : ci0, ni = mi ? ni1 : ni0;
      const float* base = Db + c*1024 + x;
      float4 fcA = *(const float4*)(base + ci*32);
      float4 fnA = *(const float4*)(base + ni*32);
      float4 fcB = *(const float4*)(base + 1024 + ci*32);
      float4 fnB = *(const float4*)(base + 1024 + ni*32);
      u16* VbM = Vb + mi*8448;
      #pragma unroll
      for (int e=0;e<4;e++){
        int xx=x+e, dp=xx&1, p=xx>>1;
        u32 dlo = f2bf(((const float*)&fnA)[e] - ((const float*)&fcA)[e]);
        u32 dhi = f2bf(((const float*)&fnB)[e] - ((const float*)&fcB)[e]);
        u32 clo = f2bf(((const float*)&fcA)[e]);
        u32 chi = f2bf(((const float*)&fcB)[e]);
        *(u32*)&VbM[p*264 + dp*128 + c]      = dlo | (dhi<<16);   // diff cols p<16
        *(u32*)&VbM[(16+p)*264 + dp*128 + c] = clo | (chi<<16);   // ctr cols p>=16
      }
    }
    // prefetch kt=0 MLP A-frags; latency hides under the barrier
    bf16x8 af0[2];
    #pragma unroll
    for (int r=0;r<2;r++) af0[r] = *(const bf16x8*)&wdb[((wv + r*4)*64+lane)*8];
    __syncthreads();
    // ---- dense MLP: C[128o x 32p] for both m; acc[r][mi*2+pt] ----
    f32x4 acc[2][4]={};
    #pragma unroll
    for (int kt=0;kt<8;kt++){
      bf16x8 bfr[4];
      #pragma unroll
      for (int mi=0;mi<2;mi++)
        #pragma unroll
        for (int pt=0;pt<2;pt++)
          bfr[mi*2+pt] = *(const bf16x8*)&Vb[mi*8448 + (pt*16+col)*264 + kt*32 + quad*8];
      #pragma unroll
      for (int r=0;r<2;r++){
        bf16x8 afr = (kt==0) ? af0[r] : *(const bf16x8*)&wdb[((kt*8+wv+r*4)*64+lane)*8];
        #pragma unroll
        for (int q=0;q<4;q++)
          acc[r][q]=__builtin_amdgcn_mfma_f32_16x16x32_bf16(afr,bfr[q],acc[r][q],0,0,0);
      }
    }
    __syncthreads();                       // Vb dead -> Bc
    { int mi=t>>7, o=t&127; Bc[mi*6272 + o*3] = 0; }   // only unwritten im2col slot: x=0,tap0
    // ---- epilogue 1: bn+gelu+max_k, scatter S[o][p] -> im2col Bc[x][o*3+tap] ----
    #pragma unroll
    for (int r=0;r<2;r++){
      #pragma unroll
      for (int mi=0;mi<2;mi++){
        u16* BcM = Bc + mi*6272;
        #pragma unroll
        for (int pt=0;pt<2;pt++){
          #pragma unroll
          for (int reg=0;reg<4;reg++){
            int o = (wv+r*4)*16 + quad*4 + reg;
            int p = pt*16 + col;
            float val = gelu_f(fmaf(acc[r][mi*2+pt][reg], Pd[o], Pd[128+o]));
            if (pt==0) val = fmaxf(val, Pd[512+o]);    // p<16: max over k
            u16 bv = f2bf(val);
            if (p&1){
              BcM[((p-1)>>1)*392 + o*3 + 2] = bv;
              if (p<31) BcM[((p+1)>>1)*392 + o*3 + 0] = bv;
            } else {
              BcM[(p>>1)*392 + o*3 + 1] = bv;
            }
          }
        }
      }
    }
    __syncthreads();
    // ---- conv: C[128o x 16x] = Wc[128o x 384k] * Bc[384k x 16x], both m ----
    f32x4 cacc[2][2]={};
    #pragma unroll
    for (int kt=0;kt<12;kt++){
      bf16x8 cb0 = *(const bf16x8*)&Bc[       col*392 + kt*32 + quad*8];
      bf16x8 cb1 = *(const bf16x8*)&Bc[6272 + col*392 + kt*32 + quad*8];
      #pragma unroll
      for (int r=0;r<2;r++){
        bf16x8 afr = *(const bf16x8*)&wcb[((kt*8+wv+r*4)*64+lane)*8];
        cacc[r][0]=__builtin_amdgcn_mfma_f32_16x16x32_bf16(afr,cb0,cacc[r][0],0,0,0);
        cacc[r][1]=__builtin_amdgcn_mfma_f32_16x16x32_bf16(afr,cb1,cacc[r][1],0,0,0);
      }
    }
    #pragma unroll
    for (int r=0;r<2;r++){
      #pragma unroll
      for (int mi=0;mi<2;mi++){
        #pragma unroll
        for (int reg=0;reg<4;reg++){
          int o = (wv+r*4)*16 + quad*4 + reg;
          float val = gelu_f(fmaf(cacc[r][mi][reg], Pd[256+o], Pd[384+o]));
          out_dn[(b*128+o)*256 + (m0+mi)*16 + col] = val;
        }
      }
    }
  }
}

extern "C" void kernel_launch(void* const* d_in, const int* in_sizes, int n_in,
                              void* d_out, int out_size, void* d_ws, size_t ws_size,
                              hipStream_t stream) {
  const float* sparse_fea = (const float*)d_in[0];
  const float* dense_fea  = (const float*)d_in[1];
  const float* stk_coor   = (const float*)d_in[2];
  // d_in[3] = n_stk_center (16, hardcoded)
  const float* sp_w  = (const float*)d_in[4];
  const float* sp_b  = (const float*)d_in[5];
  const float* sp_g  = (const float*)d_in[6];
  const float* sp_be = (const float*)d_in[7];
  const float* dn_w  = (const float*)d_in[8];
  const float* dn_b  = (const float*)d_in[9];
  const float* dn_g  = (const float*)d_in[10];
  const float* dn_be = (const float*)d_in[11];
  const float* ds_w  = (const float*)d_in[12];
  const float* ds_b  = (const float*)d_in[13];
  const float* ds_g  = (const float*)d_in[14];
  const float* ds_be = (const float*)d_in[15];

  float* out = (float*)d_out;
  // outputs: sparse [0, 524288) | dense [524288, 4718592) | coor [4718592, 4784128)
  int* fps_idx = (int*)d_ws;                              // [0, 16384) B
  int* nn_idx  = fps_idx + 2048;
  u16* wdb = (u16*)((char*)d_ws + 16384);                 // 64 KB  (8kt x 8ot)
  u16* wcb = (u16*)((char*)d_ws + 81920);                 // 96 KB  (12kt x 8ot)
  u16* wsb = (u16*)((char*)d_ws + 180224);                // 256 KB (16kt x 16ot)

  k_prep<<<960, 256, 0, stream>>>(dn_w, ds_w, sp_w, stk_coor,
                                  wdb, wcb, wsb, fps_idx, nn_idx, out + 4718592);
  k_main<<<1088, 256, 0, stream>>>(sparse_fea, wsb, sp_b, sp_g, sp_be,
                                   dense_fea, wdb, dn_b, dn_g, dn_be,
                                   wcb, ds_b, ds_g, ds_be,
                                   fps_idx, nn_idx, out, out + 524288);
}

// Round 3
// 168.109 us; speedup vs baseline: 1.1016x; 1.1016x over previous
//
#include <hip/hip_runtime.h>

// DownSample (fp32 in/out, bf16 MFMA internals), MI355X gfx950
// Shapes: B=128, n_stk=32, n_stk_pnt=32, COOR=32, m=16, k=2
// outputs: sparse_out [128,256,16] | dense_out [128,128,16,16] | coor_out [128,16,32]
//
// R11: bisection round. R10 regressed 50->77.6us with *identical* traffic
// counters and proportionally idle pipes (suspect: container variance or the
// new c-pair sparse staging, the only untested mutation). Revert sparse
// staging to the R8/R9 per-channel pattern (measured good twice); keep all
// confirmed R9/R10 dense wins: affine BN fold, 3-barrier dense path, packed
// b32 dense staging writes, kt=0 A-frag prefetch, no launch-bounds minimum.

typedef unsigned short u16;
typedef unsigned int   u32;
typedef __attribute__((ext_vector_type(8))) short bf16x8;   // 4 VGPRs
typedef __attribute__((ext_vector_type(4))) float f32x4;

#define BN_SCALE 0.9999950000374997f   // 1/sqrt(1+1e-5)

__device__ __forceinline__ float gelu_f(float x){
  return 0.5f*x*(1.0f + erff(x*0.70710678118654752f));
}
__device__ __forceinline__ u16 f2bf(float f){
  u32 x = __float_as_uint(f);
  x += 0x7fffu + ((x>>16)&1u);           // RNE
  return (u16)(x>>16);
}

// ---------------- kernel 1: weight swizzle (blocks 0..831) + FPS (832..959) ----------------
// A-frag layout: afrag[(kt*NT + ot)*64 + lane][j] = W[o = ot*16+(lane&15)][k = kt*32+((lane>>4)&3)*8+j]
__global__ __launch_bounds__(256) void k_prep(
    const float* __restrict__ dn_w, const float* __restrict__ ds_w, const float* __restrict__ sp_w,
    const float* __restrict__ coor,
    u16* __restrict__ wdb, u16* __restrict__ wcb, u16* __restrict__ wsb,
    int* __restrict__ fps_idx, int* __restrict__ nn_idx, float* __restrict__ coor_out)
{
  int blk = blockIdx.x, t = threadIdx.x;
  if (blk < 128){                       // dense MLP W [128o x 256k] -> 8kt x 8ot
    int w = blk*256 + t;
    int j=w&7, lane=(w>>3)&63, tile=w>>9;
    int kt=tile>>3, ot=tile&7;
    int o=ot*16+(lane&15), i=kt*32+((lane>>4)&3)*8+j;
    wdb[w] = f2bf(dn_w[o*256+i]);
  } else if (blk < 320){                // conv W [128o x 384k] -> 12kt x 8ot
    int w = (blk-128)*256 + t;
    int j=w&7, lane=(w>>3)&63, tile=w>>9;
    int kt=tile>>3, ot=tile&7;
    int o=ot*16+(lane&15), k=kt*32+((lane>>4)&3)*8+j;
    wcb[w] = f2bf(ds_w[o*384+k]);
  } else if (blk < 832){                // sparse W [256o x 512k] -> 16kt x 16ot
    int w = (blk-320)*256 + t;
    int j=w&7, lane=(w>>3)&63, tile=w>>9;
    int kt=tile>>4, ot=tile&15;
    int o=ot*16+(lane&15), i=kt*32+((lane>>4)&3)*8+j;
    wsb[w] = f2bf(sp_w[o*512+i]);
  } else {
    // ---- FPS + NN + coor_out for b = blk-832 ----
    int b = blk - 832;
    __shared__ float Xs[32*33];
    __shared__ float D[32*33];
    __shared__ int   s_sel[16];
    for (int i=t;i<1024;i+=256) Xs[(i>>5)*33 + (i&31)] = coor[b*1024+i];
    __syncthreads();
    #pragma unroll
    for (int k2=0;k2<4;k2++){
      int p=t+k2*256, i=p>>5, j=p&31;
      float d=0.f;
      #pragma unroll
      for (int c=0;c<32;c++){ float df=Xs[i*33+c]-Xs[j*33+c]; d+=df*df; }
      D[i*33+j]=d;
    }
    __syncthreads();
    if (t < 64){
      int j = t & 31;
      float dist = 3.0e38f;
      int far = 0;
      #pragma unroll
      for (int it=0; it<16; ++it){
        if (t==0) s_sel[it]=far;
        dist = fminf(dist, D[far*33+j]);
        float v=dist; int idx=j;              // argmax, first-index tie-break
        #pragma unroll
        for (int off=16; off>=1; off>>=1){
          float v2=__shfl_xor(v,off,32); int i2=__shfl_xor(idx,off,32);
          if (v2>v || (v2==v && i2<idx)){ v=v2; idx=i2; }
        }
        far = idx;
      }
      if (t==0){
        #pragma unroll
        for (int it=0;it<16;++it) fps_idx[b*16+it]=s_sel[it];
      }
    }
    __syncthreads();
    {
      int wv=t>>6, j=t&31;
      #pragma unroll
      for (int q=0;q<4;q++){
        int it = wv*4+q, sel = s_sel[it];
        float d = D[sel*33+j];
        if (j==sel) d=3.0e38f;
        float v=d; int idx=j;                 // argmin, first-index tie-break
        #pragma unroll
        for (int off=16; off>=1; off>>=1){
          float v2=__shfl_xor(v,off,32); int i2=__shfl_xor(idx,off,32);
          if (v2<v || (v2==v && i2<idx)){ v=v2; idx=i2; }
        }
        if ((t&63)==0) nn_idx[b*16+it]=idx;
      }
    }
    for (int q=t;q<512;q+=256){
      int mm=q>>5, c=q&31;
      coor_out[b*512+q] = Xs[s_sel[mm]*33 + c];
    }
  }
}

// ---------------- kernel 2: fused sparse (blocks 0..63, 2 b each) + dense (64..1087, 2 m each) ----
__global__ __launch_bounds__(256) void k_main(
    const float* __restrict__ sfea, const u16* __restrict__ wsb,
    const float* __restrict__ sp_b, const float* __restrict__ sp_g, const float* __restrict__ sp_be,
    const float* __restrict__ dfea, const u16* __restrict__ wdb,
    const float* __restrict__ dn_b, const float* __restrict__ dn_g, const float* __restrict__ dn_be,
    const u16* __restrict__ wcb,
    const float* __restrict__ ds_b, const float* __restrict__ ds_g, const float* __restrict__ ds_be,
    const int* __restrict__ fps_idx, const int* __restrict__ nn_idx,
    float* __restrict__ out_sp, float* __restrict__ out_dn)
{
  __shared__ char smem[36352];
  __shared__ int SI[64];
  int blk=blockIdx.x;
  int t=threadIdx.x, lane=t&63, wv=t>>6, quad=lane>>4, col=lane&15;
  if (blk < 64){
    // ======== sparse: b in {2*blk, 2*blk+1}; C = W[256o x 512i] * X[512i x 16m] x2 ========
    int b0 = blk*2;
    u16*   Xb = (u16*)smem;                      // 2 x [16m][520] u16 = 33280 B
    float* P  = (float*)(smem+33280);            // spA | spB : 512 f32 = 2048 B
    if (t<64){
      int bb=t>>5, q=t&31, b=b0+bb;
      SI[t] = ((q<16) ? fps_idx[b*16+q] : nn_idx[b*16+(q-16)]) & 31;
    }
    { float A = sp_g[t]*BN_SCALE; P[t]=A; P[256+t]=fmaf(sp_b[t],A,sp_be[t]); }
    __syncthreads();
    #pragma unroll
    for (int bb=0;bb<2;bb++){
      const float* row = sfea + (b0+bb)*8192 + t*32;   // channel t
      #pragma unroll
      for (int m=0;m<16;m++){
        float vc=row[SI[bb*32+m]], vn=row[SI[bb*32+16+m]];
        Xb[bb*8320 + m*520 + t]       = f2bf(vn-vc);   // i<256: diff
        Xb[bb*8320 + m*520 + 256 + t] = f2bf(vc);      // i>=256: ctr
      }
    }
    __syncthreads();
    #pragma unroll
    for (int oh=0;oh<2;oh++){
      f32x4 accA[2][2]={}, accB[2][2]={};        // [bb][r]
      #pragma unroll
      for (int kt=0;kt<16;kt++){
        bf16x8 bf0 = *(const bf16x8*)&Xb[        col*520 + kt*32 + quad*8];
        bf16x8 bf1 = *(const bf16x8*)&Xb[8320 +  col*520 + kt*32 + quad*8];
        #pragma unroll
        for (int r=0;r<2;r++){
          bf16x8 afr = *(const bf16x8*)&wsb[((kt*16 + oh*8 + wv + r*4)*64+lane)*8];
          if (kt<8){
            accA[0][r]=__builtin_amdgcn_mfma_f32_16x16x32_bf16(afr,bf0,accA[0][r],0,0,0);
            accA[1][r]=__builtin_amdgcn_mfma_f32_16x16x32_bf16(afr,bf1,accA[1][r],0,0,0);
          } else {
            accB[0][r]=__builtin_amdgcn_mfma_f32_16x16x32_bf16(afr,bf0,accB[0][r],0,0,0);
            accB[1][r]=__builtin_amdgcn_mfma_f32_16x16x32_bf16(afr,bf1,accB[1][r],0,0,0);
          }
        }
      }
      #pragma unroll
      for (int bb=0;bb<2;bb++){
        #pragma unroll
        for (int r=0;r<2;r++){
          #pragma unroll
          for (int reg=0;reg<4;reg++){
            int o = oh*128 + (wv+r*4)*16 + quad*4 + reg;
            float A=P[o], Bv=P[256+o];
            float k1 = accA[bb][r][reg]+accB[bb][r][reg];  // k=1: [diff|ctr]
            float k0 = accB[bb][r][reg];                   // k=0: diff part exactly 0
            float v = fmaxf(gelu_f(fmaf(k1,A,Bv)), gelu_f(fmaf(k0,A,Bv)));
            out_sp[((b0+bb)*256+o)*16 + col] = v;
          }
        }
      }
    }
  } else {
    // ======== dense: d=blk-64; b=((d>>6)<<3)|(d&7); m-pair mp=(d>>3)&7 ========
    int d=blk-64;
    int b = ((d>>6)<<3) | (d&7), m0 = ((d>>3)&7)*2;
    u16* Vb = (u16*)smem;                 // phase 1: 2 x [32p][264] bf16 = 33792 B
    u16* Bc = (u16*)smem;                 // phase 2: 2 x [16x][392] bf16 = 25088 B
    float* Pd = (float*)(smem+33792);     // dnA|dnB|dsA|dsB|a0 : 640 f32 = 2560 B
    if (t < 128){                         // fold BN: out = gelu(acc*A + B)
      float A  = dn_g[t]*BN_SCALE; float Bv = fmaf(dn_b[t], A, dn_be[t]);
      float Ac = ds_g[t]*BN_SCALE; float Cv = fmaf(ds_b[t], Ac, ds_be[t]);
      Pd[t]=A; Pd[128+t]=Bv; Pd[256+t]=Ac; Pd[384+t]=Cv;
      Pd[512+t]=gelu_f(Bv);               // a0 (k=0 diff value)
    }
    int ci0=fps_idx[b*16+m0]&31,   ni0=nn_idx[b*16+m0]&31;
    int ci1=fps_idx[b*16+m0+1]&31, ni1=nn_idx[b*16+m0+1]&31;
    const float* Db = dfea + b*131072;    // dfea[b][c][s][x]: c*1024 + s*32 + x
    #pragma unroll
    for (int it=0; it<4; it++){
      int w = t + it*256;                 // 0..1023 : mi(2) x cpair(64) x xq(8)
      int mi = w>>9, q = w&511;
      int cp = q>>3, xq = q&7;
      int c = cp*2, x = xq*4;
      int ci = mi ? ci1 : ci0, ni = mi ? ni1 : ni0;
      const float* base = Db + c*1024 + x;
      float4 fcA = *(const float4*)(base + ci*32);
      float4 fnA = *(const float4*)(base + ni*32);
      float4 fcB = *(const float4*)(base + 1024 + ci*32);
      float4 fnB = *(const float4*)(base + 1024 + ni*32);
      u16* VbM = Vb + mi*8448;
      #pragma unroll
      for (int e=0;e<4;e++){
        int xx=x+e, dp=xx&1, p=xx>>1;
        u32 dlo = f2bf(((const float*)&fnA)[e] - ((const float*)&fcA)[e]);
        u32 dhi = f2bf(((const float*)&fnB)[e] - ((const float*)&fcB)[e]);
        u32 clo = f2bf(((const float*)&fcA)[e]);
        u32 chi = f2bf(((const float*)&fcB)[e]);
        *(u32*)&VbM[p*264 + dp*128 + c]      = dlo | (dhi<<16);   // diff cols p<16
        *(u32*)&VbM[(16+p)*264 + dp*128 + c] = clo | (chi<<16);   // ctr cols p>=16
      }
    }
    // prefetch kt=0 MLP A-frags; latency hides under the barrier
    bf16x8 af0[2];
    #pragma unroll
    for (int r=0;r<2;r++) af0[r] = *(const bf16x8*)&wdb[((wv + r*4)*64+lane)*8];
    __syncthreads();
    // ---- dense MLP: C[128o x 32p] for both m; acc[r][mi*2+pt] ----
    f32x4 acc[2][4]={};
    #pragma unroll
    for (int kt=0;kt<8;kt++){
      bf16x8 bfr[4];
      #pragma unroll
      for (int mi=0;mi<2;mi++)
        #pragma unroll
        for (int pt=0;pt<2;pt++)
          bfr[mi*2+pt] = *(const bf16x8*)&Vb[mi*8448 + (pt*16+col)*264 + kt*32 + quad*8];
      #pragma unroll
      for (int r=0;r<2;r++){
        bf16x8 afr = (kt==0) ? af0[r] : *(const bf16x8*)&wdb[((kt*8+wv+r*4)*64+lane)*8];
        #pragma unroll
        for (int q=0;q<4;q++)
          acc[r][q]=__builtin_amdgcn_mfma_f32_16x16x32_bf16(afr,bfr[q],acc[r][q],0,0,0);
      }
    }
    __syncthreads();                       // Vb dead -> Bc
    { int mi=t>>7, o=t&127; Bc[mi*6272 + o*3] = 0; }   // only unwritten im2col slot: x=0,tap0
    // ---- epilogue 1: bn+gelu+max_k, scatter S[o][p] -> im2col Bc[x][o*3+tap] ----
    #pragma unroll
    for (int r=0;r<2;r++){
      #pragma unroll
      for (int mi=0;mi<2;mi++){
        u16* BcM = Bc + mi*6272;
        #pragma unroll
        for (int pt=0;pt<2;pt++){
          #pragma unroll
          for (int reg=0;reg<4;reg++){
            int o = (wv+r*4)*16 + quad*4 + reg;
            int p = pt*16 + col;
            float val = gelu_f(fmaf(acc[r][mi*2+pt][reg], Pd[o], Pd[128+o]));
            if (pt==0) val = fmaxf(val, Pd[512+o]);    // p<16: max over k
            u16 bv = f2bf(val);
            if (p&1){
              BcM[((p-1)>>1)*392 + o*3 + 2] = bv;
              if (p<31) BcM[((p+1)>>1)*392 + o*3 + 0] = bv;
            } else {
              BcM[(p>>1)*392 + o*3 + 1] = bv;
            }
          }
        }
      }
    }
    __syncthreads();
    // ---- conv: C[128o x 16x] = Wc[128o x 384k] * Bc[384k x 16x], both m ----
    f32x4 cacc[2][2]={};
    #pragma unroll
    for (int kt=0;kt<12;kt++){
      bf16x8 cb0 = *(const bf16x8*)&Bc[       col*392 + kt*32 + quad*8];
      bf16x8 cb1 = *(const bf16x8*)&Bc[6272 + col*392 + kt*32 + quad*8];
      #pragma unroll
      for (int r=0;r<2;r++){
        bf16x8 afr = *(const bf16x8*)&wcb[((kt*8+wv+r*4)*64+lane)*8];
        cacc[r][0]=__builtin_amdgcn_mfma_f32_16x16x32_bf16(afr,cb0,cacc[r][0],0,0,0);
        cacc[r][1]=__builtin_amdgcn_mfma_f32_16x16x32_bf16(afr,cb1,cacc[r][1],0,0,0);
      }
    }
    #pragma unroll
    for (int r=0;r<2;r++){
      #pragma unroll
      for (int mi=0;mi<2;mi++){
        #pragma unroll
        for (int reg=0;reg<4;reg++){
          int o = (wv+r*4)*16 + quad*4 + reg;
          float val = gelu_f(fmaf(cacc[r][mi][reg], Pd[256+o], Pd[384+o]));
          out_dn[(b*128+o)*256 + (m0+mi)*16 + col] = val;
        }
      }
    }
  }
}

extern "C" void kernel_launch(void* const* d_in, const int* in_sizes, int n_in,
                              void* d_out, int out_size, void* d_ws, size_t ws_size,
                              hipStream_t stream) {
  const float* sparse_fea = (const float*)d_in[0];
  const float* dense_fea  = (const float*)d_in[1];
  const float* stk_coor   = (const float*)d_in[2];
  // d_in[3] = n_stk_center (16, hardcoded)
  const float* sp_w  = (const float*)d_in[4];
  const float* sp_b  = (const float*)d_in[5];
  const float* sp_g  = (const float*)d_in[6];
  const float* sp_be = (const float*)d_in[7];
  const float* dn_w  = (const float*)d_in[8];
  const float* dn_b  = (const float*)d_in[9];
  const float* dn_g  = (const float*)d_in[10];
  const float* dn_be = (const float*)d_in[11];
  const float* ds_w  = (const float*)d_in[12];
  const float* ds_b  = (const float*)d_in[13];
  const float* ds_g  = (const float*)d_in[14];
  const float* ds_be = (const float*)d_in[15];

  float* out = (float*)d_out;
  // outputs: sparse [0, 524288) | dense [524288, 4718592) | coor [4718592, 4784128)
  int* fps_idx = (int*)d_ws;                              // [0, 16384) B
  int* nn_idx  = fps_idx + 2048;
  u16* wdb = (u16*)((char*)d_ws + 16384);                 // 64 KB  (8kt x 8ot)
  u16* wcb = (u16*)((char*)d_ws + 81920);                 // 96 KB  (12kt x 8ot)
  u16* wsb = (u16*)((char*)d_ws + 180224);                // 256 KB (16kt x 16ot)

  k_prep<<<960, 256, 0, stream>>>(dn_w, ds_w, sp_w, stk_coor,
                                  wdb, wcb, wsb, fps_idx, nn_idx, out + 4718592);
  k_main<<<1088, 256, 0, stream>>>(sparse_fea, wsb, sp_b, sp_g, sp_be,
                                   dense_fea, wdb, dn_b, dn_g, dn_be,
                                   wcb, ds_b, ds_g, ds_be,
                                   fps_idx, nn_idx, out, out + 524288);
}

// Round 4
// 166.810 us; speedup vs baseline: 1.1102x; 1.0078x over previous
//
#include <hip/hip_runtime.h>

// DownSample (fp32 in/out, bf16 MFMA internals), MI355X gfx950
// Shapes: B=128, n_stk=32, n_stk_pnt=32, COOR=32, m=16, k=2
// outputs: sparse_out [128,256,16] | dense_out [128,128,16,16] | coor_out [128,16,32]
//
// R12: occupancy round. R11 diagnosis: 28% combined issue at 4 waves/SIMD,
// waves stalled 72% on ds_read/L2/erf latency; VGPR=112 and LDS=36.9KB both
// cap at 4 blocks/CU. Restructure to 1 m per dense block (2048) and 1 b per
// sparse block (128): LDS ~19.4KB, half the register state, and
// __launch_bounds__(256,6) caps VGPR ~80 -> 6 blocks/CU (+50% waves).
// Same arithmetic as R11 (bit-identical outputs).

typedef unsigned short u16;
typedef unsigned int   u32;
typedef __attribute__((ext_vector_type(8))) short bf16x8;   // 4 VGPRs
typedef __attribute__((ext_vector_type(4))) float f32x4;

#define BN_SCALE 0.9999950000374997f   // 1/sqrt(1+1e-5)

__device__ __forceinline__ float gelu_f(float x){
  return 0.5f*x*(1.0f + erff(x*0.70710678118654752f));
}
__device__ __forceinline__ u16 f2bf(float f){
  u32 x = __float_as_uint(f);
  x += 0x7fffu + ((x>>16)&1u);           // RNE
  return (u16)(x>>16);
}

// ---------------- kernel 1: weight swizzle (blocks 0..831) + FPS (832..959) ----------------
// A-frag layout: afrag[(kt*NT + ot)*64 + lane][j] = W[o = ot*16+(lane&15)][k = kt*32+((lane>>4)&3)*8+j]
__global__ __launch_bounds__(256) void k_prep(
    const float* __restrict__ dn_w, const float* __restrict__ ds_w, const float* __restrict__ sp_w,
    const float* __restrict__ coor,
    u16* __restrict__ wdb, u16* __restrict__ wcb, u16* __restrict__ wsb,
    int* __restrict__ fps_idx, int* __restrict__ nn_idx, float* __restrict__ coor_out)
{
  int blk = blockIdx.x, t = threadIdx.x;
  if (blk < 128){                       // dense MLP W [128o x 256k] -> 8kt x 8ot
    int w = blk*256 + t;
    int j=w&7, lane=(w>>3)&63, tile=w>>9;
    int kt=tile>>3, ot=tile&7;
    int o=ot*16+(lane&15), i=kt*32+((lane>>4)&3)*8+j;
    wdb[w] = f2bf(dn_w[o*256+i]);
  } else if (blk < 320){                // conv W [128o x 384k] -> 12kt x 8ot
    int w = (blk-128)*256 + t;
    int j=w&7, lane=(w>>3)&63, tile=w>>9;
    int kt=tile>>3, ot=tile&7;
    int o=ot*16+(lane&15), k=kt*32+((lane>>4)&3)*8+j;
    wcb[w] = f2bf(ds_w[o*384+k]);
  } else if (blk < 832){                // sparse W [256o x 512k] -> 16kt x 16ot
    int w = (blk-320)*256 + t;
    int j=w&7, lane=(w>>3)&63, tile=w>>9;
    int kt=tile>>4, ot=tile&15;
    int o=ot*16+(lane&15), i=kt*32+((lane>>4)&3)*8+j;
    wsb[w] = f2bf(sp_w[o*512+i]);
  } else {
    // ---- FPS + NN + coor_out for b = blk-832 ----
    int b = blk - 832;
    __shared__ float Xs[32*33];
    __shared__ float D[32*33];
    __shared__ int   s_sel[16];
    for (int i=t;i<1024;i+=256) Xs[(i>>5)*33 + (i&31)] = coor[b*1024+i];
    __syncthreads();
    #pragma unroll
    for (int k2=0;k2<4;k2++){
      int p=t+k2*256, i=p>>5, j=p&31;
      float d=0.f;
      #pragma unroll
      for (int c=0;c<32;c++){ float df=Xs[i*33+c]-Xs[j*33+c]; d+=df*df; }
      D[i*33+j]=d;
    }
    __syncthreads();
    if (t < 64){
      int j = t & 31;
      float dist = 3.0e38f;
      int far = 0;
      #pragma unroll
      for (int it=0; it<16; ++it){
        if (t==0) s_sel[it]=far;
        dist = fminf(dist, D[far*33+j]);
        float v=dist; int idx=j;              // argmax, first-index tie-break
        #pragma unroll
        for (int off=16; off>=1; off>>=1){
          float v2=__shfl_xor(v,off,32); int i2=__shfl_xor(idx,off,32);
          if (v2>v || (v2==v && i2<idx)){ v=v2; idx=i2; }
        }
        far = idx;
      }
      if (t==0){
        #pragma unroll
        for (int it=0;it<16;++it) fps_idx[b*16+it]=s_sel[it];
      }
    }
    __syncthreads();
    {
      int wv=t>>6, j=t&31;
      #pragma unroll
      for (int q=0;q<4;q++){
        int it = wv*4+q, sel = s_sel[it];
        float d = D[sel*33+j];
        if (j==sel) d=3.0e38f;
        float v=d; int idx=j;                 // argmin, first-index tie-break
        #pragma unroll
        for (int off=16; off>=1; off>>=1){
          float v2=__shfl_xor(v,off,32); int i2=__shfl_xor(idx,off,32);
          if (v2<v || (v2==v && i2<idx)){ v=v2; idx=i2; }
        }
        if ((t&63)==0) nn_idx[b*16+it]=idx;
      }
    }
    for (int q=t;q<512;q+=256){
      int mm=q>>5, c=q&31;
      coor_out[b*512+q] = Xs[s_sel[mm]*33 + c];
    }
  }
}

// ---------------- kernel 2: fused sparse (blocks 0..127, 1 b each) + dense (128..2175, 1 m each) ----
__global__ __launch_bounds__(256,6) void k_main(
    const float* __restrict__ sfea, const u16* __restrict__ wsb,
    const float* __restrict__ sp_b, const float* __restrict__ sp_g, const float* __restrict__ sp_be,
    const float* __restrict__ dfea, const u16* __restrict__ wdb,
    const float* __restrict__ dn_b, const float* __restrict__ dn_g, const float* __restrict__ dn_be,
    const u16* __restrict__ wcb,
    const float* __restrict__ ds_b, const float* __restrict__ ds_g, const float* __restrict__ ds_be,
    const int* __restrict__ fps_idx, const int* __restrict__ nn_idx,
    float* __restrict__ out_sp, float* __restrict__ out_dn)
{
  __shared__ char smem[19456];
  __shared__ int SI[32];
  int blk=blockIdx.x;
  int t=threadIdx.x, lane=t&63, wv=t>>6, quad=lane>>4, col=lane&15;
  if (blk < 128){
    // ======== sparse: b = blk; C = W[256o x 512i] * X[512i x 16m] ========
    int b = blk;
    u16*   Xb = (u16*)smem;                      // [16m][520] u16 = 16640 B
    float* P  = (float*)(smem+16640);            // spA | spB : 512 f32 = 2048 B
    if (t<32){
      SI[t] = ((t<16) ? fps_idx[b*16+t] : nn_idx[b*16+(t-16)]) & 31;
    }
    { float A = sp_g[t]*BN_SCALE; P[t]=A; P[256+t]=fmaf(sp_b[t],A,sp_be[t]); }
    __syncthreads();
    {
      const float* row = sfea + b*8192 + t*32;   // channel t
      #pragma unroll
      for (int m=0;m<16;m++){
        float vc=row[SI[m]], vn=row[SI[16+m]];
        Xb[m*520 + t]       = f2bf(vn-vc);   // i<256: diff
        Xb[m*520 + 256 + t] = f2bf(vc);      // i>=256: ctr
      }
    }
    __syncthreads();
    #pragma unroll
    for (int oh=0;oh<2;oh++){
      f32x4 accA[2]={}, accB[2]={};              // [r]
      #pragma unroll
      for (int kt=0;kt<16;kt++){
        bf16x8 bf0 = *(const bf16x8*)&Xb[col*520 + kt*32 + quad*8];
        #pragma unroll
        for (int r=0;r<2;r++){
          bf16x8 afr = *(const bf16x8*)&wsb[((kt*16 + oh*8 + wv + r*4)*64+lane)*8];
          if (kt<8) accA[r]=__builtin_amdgcn_mfma_f32_16x16x32_bf16(afr,bf0,accA[r],0,0,0);
          else      accB[r]=__builtin_amdgcn_mfma_f32_16x16x32_bf16(afr,bf0,accB[r],0,0,0);
        }
      }
      #pragma unroll
      for (int r=0;r<2;r++){
        #pragma unroll
        for (int reg=0;reg<4;reg++){
          int o = oh*128 + (wv+r*4)*16 + quad*4 + reg;
          float A=P[o], Bv=P[256+o];
          float k1 = accA[r][reg]+accB[r][reg];  // k=1: [diff|ctr]
          float k0 = accB[r][reg];               // k=0: diff part exactly 0
          float v = fmaxf(gelu_f(fmaf(k1,A,Bv)), gelu_f(fmaf(k0,A,Bv)));
          out_sp[(b*256+o)*16 + col] = v;
        }
      }
    }
  } else {
    // ======== dense: d=blk-128; b=((d>>7)<<3)|(d&7); m=(d>>3)&15 ========
    int d=blk-128;
    int b = ((d>>7)<<3) | (d&7), m = (d>>3)&15;
    u16* Vb = (u16*)smem;                 // phase 1: [32p][264] bf16 = 16896 B
    u16* Bc = (u16*)smem;                 // phase 2: [16x][392] bf16 = 12544 B
    float* Pd = (float*)(smem+16896);     // dnA|dnB|dsA|dsB|a0 : 640 f32 = 2560 B
    if (t < 128){                         // fold BN: out = gelu(acc*A + B)
      float A  = dn_g[t]*BN_SCALE; float Bv = fmaf(dn_b[t], A, dn_be[t]);
      float Ac = ds_g[t]*BN_SCALE; float Cv = fmaf(ds_b[t], Ac, ds_be[t]);
      Pd[t]=A; Pd[128+t]=Bv; Pd[256+t]=Ac; Pd[384+t]=Cv;
      Pd[512+t]=gelu_f(Bv);               // a0 (k=0 diff value)
    }
    int ci=fps_idx[b*16+m]&31, ni=nn_idx[b*16+m]&31;
    const float* Db = dfea + b*131072;    // dfea[b][c][s][x]: c*1024 + s*32 + x
    #pragma unroll
    for (int it=0; it<2; it++){
      int w = t + it*256;                 // 0..511 : cpair(64) x xq(8)
      int cp = w>>3, xq = w&7;
      int c = cp*2, x = xq*4;
      const float* base = Db + c*1024 + x;
      float4 fcA = *(const float4*)(base + ci*32);
      float4 fnA = *(const float4*)(base + ni*32);
      float4 fcB = *(const float4*)(base + 1024 + ci*32);
      float4 fnB = *(const float4*)(base + 1024 + ni*32);
      #pragma unroll
      for (int e=0;e<4;e++){
        int xx=x+e, dp=xx&1, p=xx>>1;
        u32 dlo = f2bf(((const float*)&fnA)[e] - ((const float*)&fcA)[e]);
        u32 dhi = f2bf(((const float*)&fnB)[e] - ((const float*)&fcB)[e]);
        u32 clo = f2bf(((const float*)&fcA)[e]);
        u32 chi = f2bf(((const float*)&fcB)[e]);
        *(u32*)&Vb[p*264 + dp*128 + c]      = dlo | (dhi<<16);   // diff cols p<16
        *(u32*)&Vb[(16+p)*264 + dp*128 + c] = clo | (chi<<16);   // ctr cols p>=16
      }
    }
    // prefetch kt=0 MLP A-frags; latency hides under the barrier
    bf16x8 af0[2];
    #pragma unroll
    for (int r=0;r<2;r++) af0[r] = *(const bf16x8*)&wdb[((wv + r*4)*64+lane)*8];
    __syncthreads();
    // ---- dense MLP: C[128o x 32p]; acc[r][pt] ----
    f32x4 acc[2][2]={};
    #pragma unroll
    for (int kt=0;kt<8;kt++){
      bf16x8 bfr[2];
      #pragma unroll
      for (int pt=0;pt<2;pt++)
        bfr[pt] = *(const bf16x8*)&Vb[(pt*16+col)*264 + kt*32 + quad*8];
      #pragma unroll
      for (int r=0;r<2;r++){
        bf16x8 afr = (kt==0) ? af0[r] : *(const bf16x8*)&wdb[((kt*8+wv+r*4)*64+lane)*8];
        #pragma unroll
        for (int pt=0;pt<2;pt++)
          acc[r][pt]=__builtin_amdgcn_mfma_f32_16x16x32_bf16(afr,bfr[pt],acc[r][pt],0,0,0);
      }
    }
    __syncthreads();                       // Vb dead -> Bc
    if (t<128) Bc[t*3] = 0;                // only unwritten im2col slot: x=0,tap0 (o=t)
    // ---- epilogue 1: bn+gelu+max_k, scatter S[o][p] -> im2col Bc[x][o*3+tap] ----
    #pragma unroll
    for (int r=0;r<2;r++){
      #pragma unroll
      for (int pt=0;pt<2;pt++){
        #pragma unroll
        for (int reg=0;reg<4;reg++){
          int o = (wv+r*4)*16 + quad*4 + reg;
          int p = pt*16 + col;
          float val = gelu_f(fmaf(acc[r][pt][reg], Pd[o], Pd[128+o]));
          if (pt==0) val = fmaxf(val, Pd[512+o]);    // p<16: max over k
          u16 bv = f2bf(val);
          if (p&1){
            Bc[((p-1)>>1)*392 + o*3 + 2] = bv;
            if (p<31) Bc[((p+1)>>1)*392 + o*3 + 0] = bv;
          } else {
            Bc[(p>>1)*392 + o*3 + 1] = bv;
          }
        }
      }
    }
    __syncthreads();
    // ---- conv: C[128o x 16x] = Wc[128o x 384k] * Bc[384k x 16x] ----
    f32x4 cacc[2]={};
    #pragma unroll
    for (int kt=0;kt<12;kt++){
      bf16x8 cb0 = *(const bf16x8*)&Bc[col*392 + kt*32 + quad*8];
      #pragma unroll
      for (int r=0;r<2;r++){
        bf16x8 afr = *(const bf16x8*)&wcb[((kt*8+wv+r*4)*64+lane)*8];
        cacc[r]=__builtin_amdgcn_mfma_f32_16x16x32_bf16(afr,cb0,cacc[r],0,0,0);
      }
    }
    #pragma unroll
    for (int r=0;r<2;r++){
      #pragma unroll
      for (int reg=0;reg<4;reg++){
        int o = (wv+r*4)*16 + quad*4 + reg;
        float val = gelu_f(fmaf(cacc[r][reg], Pd[256+o], Pd[384+o]));
        out_dn[(b*128+o)*256 + m*16 + col] = val;
      }
    }
  }
}

extern "C" void kernel_launch(void* const* d_in, const int* in_sizes, int n_in,
                              void* d_out, int out_size, void* d_ws, size_t ws_size,
                              hipStream_t stream) {
  const float* sparse_fea = (const float*)d_in[0];
  const float* dense_fea  = (const float*)d_in[1];
  const float* stk_coor   = (const float*)d_in[2];
  // d_in[3] = n_stk_center (16, hardcoded)
  const float* sp_w  = (const float*)d_in[4];
  const float* sp_b  = (const float*)d_in[5];
  const float* sp_g  = (const float*)d_in[6];
  const float* sp_be = (const float*)d_in[7];
  const float* dn_w  = (const float*)d_in[8];
  const float* dn_b  = (const float*)d_in[9];
  const float* dn_g  = (const float*)d_in[10];
  const float* dn_be = (const float*)d_in[11];
  const float* ds_w  = (const float*)d_in[12];
  const float* ds_b  = (const float*)d_in[13];
  const float* ds_g  = (const float*)d_in[14];
  const float* ds_be = (const float*)d_in[15];

  float* out = (float*)d_out;
  // outputs: sparse [0, 524288) | dense [524288, 4718592) | coor [4718592, 4784128)
  int* fps_idx = (int*)d_ws;                              // [0, 16384) B
  int* nn_idx  = fps_idx + 2048;
  u16* wdb = (u16*)((char*)d_ws + 16384);                 // 64 KB  (8kt x 8ot)
  u16* wcb = (u16*)((char*)d_ws + 81920);                 // 96 KB  (12kt x 8ot)
  u16* wsb = (u16*)((char*)d_ws + 180224);                // 256 KB (16kt x 16ot)

  k_prep<<<960, 256, 0, stream>>>(dn_w, ds_w, sp_w, stk_coor,
                                  wdb, wcb, wsb, fps_idx, nn_idx, out + 4718592);
  k_main<<<2176, 256, 0, stream>>>(sparse_fea, wsb, sp_b, sp_g, sp_be,
                                   dense_fea, wdb, dn_b, dn_g, dn_be,
                                   wcb, ds_b, ds_g, ds_be,
                                   fps_idx, nn_idx, out, out + 524288);
}

// Round 5
// 162.600 us; speedup vs baseline: 1.1389x; 1.0259x over previous
//
#include <hip/hip_runtime.h>

// DownSample (fp32 in/out, bf16 MFMA internals), MI355X gfx950
// Shapes: B=128, n_stk=32, n_stk_pnt=32, COOR=32, m=16, k=2
// outputs: sparse_out [128,256,16] | dense_out [128,128,16,16] | coor_out [128,16,32]
//
// R13: ILP round. R12 hit 8 blocks/CU but VGPR=40 -> ~2 weight loads in
// flight; 16 (MLP) + 24 (conv) L2 loads serialize into ~250cy round-trips.
// Force 8-deep load pipelines: Rf[8] stage batch, wf[8]/cwf[8] rolling
// A-frag chunks (load slot's replacement right after consumption), conv
// chunk0 prefetched under the epi barrier. launch_bounds(256,6): 85-VGPR
// cap, 6-7 blocks/CU. Same arithmetic, bit-identical outputs.

typedef unsigned short u16;
typedef unsigned int   u32;
typedef __attribute__((ext_vector_type(8))) short bf16x8;   // 4 VGPRs
typedef __attribute__((ext_vector_type(4))) float f32x4;

#define BN_SCALE 0.9999950000374997f   // 1/sqrt(1+1e-5)

__device__ __forceinline__ float gelu_f(float x){
  return 0.5f*x*(1.0f + erff(x*0.70710678118654752f));
}
__device__ __forceinline__ u16 f2bf(float f){
  u32 x = __float_as_uint(f);
  x += 0x7fffu + ((x>>16)&1u);           // RNE
  return (u16)(x>>16);
}
#define MFMA16(a,b,c) __builtin_amdgcn_mfma_f32_16x16x32_bf16(a,b,c,0,0,0)

// ---------------- kernel 1: weight swizzle (blocks 0..831) + FPS (832..959) ----------------
// A-frag layout: afrag[(kt*NT + ot)*64 + lane][j] = W[o = ot*16+(lane&15)][k = kt*32+((lane>>4)&3)*8+j]
__global__ __launch_bounds__(256) void k_prep(
    const float* __restrict__ dn_w, const float* __restrict__ ds_w, const float* __restrict__ sp_w,
    const float* __restrict__ coor,
    u16* __restrict__ wdb, u16* __restrict__ wcb, u16* __restrict__ wsb,
    int* __restrict__ fps_idx, int* __restrict__ nn_idx, float* __restrict__ coor_out)
{
  int blk = blockIdx.x, t = threadIdx.x;
  if (blk < 128){                       // dense MLP W [128o x 256k] -> 8kt x 8ot
    int w = blk*256 + t;
    int j=w&7, lane=(w>>3)&63, tile=w>>9;
    int kt=tile>>3, ot=tile&7;
    int o=ot*16+(lane&15), i=kt*32+((lane>>4)&3)*8+j;
    wdb[w] = f2bf(dn_w[o*256+i]);
  } else if (blk < 320){                // conv W [128o x 384k] -> 12kt x 8ot
    int w = (blk-128)*256 + t;
    int j=w&7, lane=(w>>3)&63, tile=w>>9;
    int kt=tile>>3, ot=tile&7;
    int o=ot*16+(lane&15), k=kt*32+((lane>>4)&3)*8+j;
    wcb[w] = f2bf(ds_w[o*384+k]);
  } else if (blk < 832){                // sparse W [256o x 512k] -> 16kt x 16ot
    int w = (blk-320)*256 + t;
    int j=w&7, lane=(w>>3)&63, tile=w>>9;
    int kt=tile>>4, ot=tile&15;
    int o=ot*16+(lane&15), i=kt*32+((lane>>4)&3)*8+j;
    wsb[w] = f2bf(sp_w[o*512+i]);
  } else {
    // ---- FPS + NN + coor_out for b = blk-832 ----
    int b = blk - 832;
    __shared__ float Xs[32*33];
    __shared__ float D[32*33];
    __shared__ int   s_sel[16];
    for (int i=t;i<1024;i+=256) Xs[(i>>5)*33 + (i&31)] = coor[b*1024+i];
    __syncthreads();
    #pragma unroll
    for (int k2=0;k2<4;k2++){
      int p=t+k2*256, i=p>>5, j=p&31;
      float d=0.f;
      #pragma unroll
      for (int c=0;c<32;c++){ float df=Xs[i*33+c]-Xs[j*33+c]; d+=df*df; }
      D[i*33+j]=d;
    }
    __syncthreads();
    if (t < 64){
      int j = t & 31;
      float dist = 3.0e38f;
      int far = 0;
      #pragma unroll
      for (int it=0; it<16; ++it){
        if (t==0) s_sel[it]=far;
        dist = fminf(dist, D[far*33+j]);
        float v=dist; int idx=j;              // argmax, first-index tie-break
        #pragma unroll
        for (int off=16; off>=1; off>>=1){
          float v2=__shfl_xor(v,off,32); int i2=__shfl_xor(idx,off,32);
          if (v2>v || (v2==v && i2<idx)){ v=v2; idx=i2; }
        }
        far = idx;
      }
      if (t==0){
        #pragma unroll
        for (int it=0;it<16;++it) fps_idx[b*16+it]=s_sel[it];
      }
    }
    __syncthreads();
    {
      int wv=t>>6, j=t&31;
      #pragma unroll
      for (int q=0;q<4;q++){
        int it = wv*4+q, sel = s_sel[it];
        float d = D[sel*33+j];
        if (j==sel) d=3.0e38f;
        float v=d; int idx=j;                 // argmin, first-index tie-break
        #pragma unroll
        for (int off=16; off>=1; off>>=1){
          float v2=__shfl_xor(v,off,32); int i2=__shfl_xor(idx,off,32);
          if (v2<v || (v2==v && i2<idx)){ v=v2; idx=i2; }
        }
        if ((t&63)==0) nn_idx[b*16+it]=idx;
      }
    }
    for (int q=t;q<512;q+=256){
      int mm=q>>5, c=q&31;
      coor_out[b*512+q] = Xs[s_sel[mm]*33 + c];
    }
  }
}

// ---------------- kernel 2: fused sparse (blocks 0..127, 1 b each) + dense (128..2175, 1 m each) ----
__global__ __launch_bounds__(256,6) void k_main(
    const float* __restrict__ sfea, const u16* __restrict__ wsb,
    const float* __restrict__ sp_b, const float* __restrict__ sp_g, const float* __restrict__ sp_be,
    const float* __restrict__ dfea, const u16* __restrict__ wdb,
    const float* __restrict__ dn_b, const float* __restrict__ dn_g, const float* __restrict__ dn_be,
    const u16* __restrict__ wcb,
    const float* __restrict__ ds_b, const float* __restrict__ ds_g, const float* __restrict__ ds_be,
    const int* __restrict__ fps_idx, const int* __restrict__ nn_idx,
    float* __restrict__ out_sp, float* __restrict__ out_dn)
{
  __shared__ char smem[19456];
  __shared__ int SI[32];
  int blk=blockIdx.x;
  int t=threadIdx.x, lane=t&63, wv=t>>6, quad=lane>>4, col=lane&15;
  if (blk < 128){
    // ======== sparse: b = blk; C = W[256o x 512i] * X[512i x 16m] ========
    int b = blk;
    u16*   Xb = (u16*)smem;                      // [16m][520] u16 = 16640 B
    float* P  = (float*)(smem+16640);            // spA | spB : 512 f32 = 2048 B
    if (t<32){
      SI[t] = ((t<16) ? fps_idx[b*16+t] : nn_idx[b*16+(t-16)]) & 31;
    }
    { float A = sp_g[t]*BN_SCALE; P[t]=A; P[256+t]=fmaf(sp_b[t],A,sp_be[t]); }
    __syncthreads();
    {
      const float* row = sfea + b*8192 + t*32;   // channel t
      #pragma unroll
      for (int m=0;m<16;m++){
        float vc=row[SI[m]], vn=row[SI[16+m]];
        Xb[m*520 + t]       = f2bf(vn-vc);   // i<256: diff
        Xb[m*520 + 256 + t] = f2bf(vc);      // i>=256: ctr
      }
    }
    // prefetch A-frag chunk (oh=0, kt=0..3) x 2r -> 8-deep; hides under barrier
    bf16x8 wf[8];
    #pragma unroll
    for (int kk=0;kk<4;kk++){
      wf[kk*2]   = *(const bf16x8*)&wsb[((kk*16 + wv    )*64+lane)*8];
      wf[kk*2+1] = *(const bf16x8*)&wsb[((kk*16 + wv + 4)*64+lane)*8];
    }
    __syncthreads();
    #pragma unroll
    for (int oh=0;oh<2;oh++){
      f32x4 accA[2]={}, accB[2]={};              // [r]
      #pragma unroll
      for (int kc=0;kc<4;kc++){
        #pragma unroll
        for (int kk=0;kk<4;kk++){
          int kt = kc*4+kk;
          bf16x8 a0=wf[kk*2], a1=wf[kk*2+1];
          int g = oh*4+kc;                       // rolling prefetch of next chunk's slot
          if (g<7){
            int g2=g+1, oh2=g2>>2, kc2=g2&3, kt2=kc2*4+kk;
            wf[kk*2]   = *(const bf16x8*)&wsb[((kt2*16 + oh2*8 + wv    )*64+lane)*8];
            wf[kk*2+1] = *(const bf16x8*)&wsb[((kt2*16 + oh2*8 + wv + 4)*64+lane)*8];
          }
          bf16x8 bf0 = *(const bf16x8*)&Xb[col*520 + kt*32 + quad*8];
          if (kt<8){ accA[0]=MFMA16(a0,bf0,accA[0]); accA[1]=MFMA16(a1,bf0,accA[1]); }
          else     { accB[0]=MFMA16(a0,bf0,accB[0]); accB[1]=MFMA16(a1,bf0,accB[1]); }
        }
      }
      #pragma unroll
      for (int r=0;r<2;r++){
        #pragma unroll
        for (int reg=0;reg<4;reg++){
          int o = oh*128 + (wv+r*4)*16 + quad*4 + reg;
          float A=P[o], Bv=P[256+o];
          float k1 = accA[r][reg]+accB[r][reg];  // k=1: [diff|ctr]
          float k0 = accB[r][reg];               // k=0: diff part exactly 0
          float v = fmaxf(gelu_f(fmaf(k1,A,Bv)), gelu_f(fmaf(k0,A,Bv)));
          out_sp[(b*256+o)*16 + col] = v;
        }
      }
    }
  } else {
    // ======== dense: d=blk-128; b=((d>>7)<<3)|(d&7); m=(d>>3)&15 ========
    int d=blk-128;
    int b = ((d>>7)<<3) | (d&7), m = (d>>3)&15;
    u16* Vb = (u16*)smem;                 // phase 1: [32p][264] bf16 = 16896 B
    u16* Bc = (u16*)smem;                 // phase 2: [16x][392] bf16 = 12544 B
    float* Pd = (float*)(smem+16896);     // dnA|dnB|dsA|dsB|a0 : 640 f32 = 2560 B
    // gather indices first: they head the critical path (address -> 8 gathers)
    int ci=fps_idx[b*16+m]&31, ni=nn_idx[b*16+m]&31;
    if (t < 128){                         // fold BN: out = gelu(acc*A + B)
      float A  = dn_g[t]*BN_SCALE; float Bv = fmaf(dn_b[t], A, dn_be[t]);
      float Ac = ds_g[t]*BN_SCALE; float Cv = fmaf(ds_b[t], Ac, ds_be[t]);
      Pd[t]=A; Pd[128+t]=Bv; Pd[256+t]=Ac; Pd[384+t]=Cv;
      Pd[512+t]=gelu_f(Bv);               // a0 (k=0 diff value)
    }
    const float* Db = dfea + b*131072;    // dfea[b][c][s][x]: c*1024 + s*32 + x
    // ---- stage: batch all 8 gathers 8-deep, then pack ----
    float4 Rf[8];
    #pragma unroll
    for (int it=0; it<2; it++){
      int w = t + it*256;                 // 0..511 : cpair(64) x xq(8)
      int c = (w>>3)*2, x = (w&7)*4;
      const float* base = Db + c*1024 + x;
      Rf[it*4+0] = *(const float4*)(base + ci*32);
      Rf[it*4+1] = *(const float4*)(base + ni*32);
      Rf[it*4+2] = *(const float4*)(base + 1024 + ci*32);
      Rf[it*4+3] = *(const float4*)(base + 1024 + ni*32);
    }
    #pragma unroll
    for (int it=0; it<2; it++){
      int w = t + it*256;
      int c = (w>>3)*2, x = (w&7)*4;
      float4 fcA=Rf[it*4+0], fnA=Rf[it*4+1], fcB=Rf[it*4+2], fnB=Rf[it*4+3];
      #pragma unroll
      for (int e=0;e<4;e++){
        int xx=x+e, dp=xx&1, p=xx>>1;
        u32 dlo = f2bf(((const float*)&fnA)[e] - ((const float*)&fcA)[e]);
        u32 dhi = f2bf(((const float*)&fnB)[e] - ((const float*)&fcB)[e]);
        u32 clo = f2bf(((const float*)&fcA)[e]);
        u32 chi = f2bf(((const float*)&fcB)[e]);
        *(u32*)&Vb[p*264 + dp*128 + c]      = dlo | (dhi<<16);   // diff cols p<16
        *(u32*)&Vb[(16+p)*264 + dp*128 + c] = clo | (chi<<16);   // ctr cols p>=16
      }
    }
    // prefetch MLP A-frag chunk0 (kt 0..3 x 2r), 8-deep; hides under barrier
    bf16x8 wf[8];
    #pragma unroll
    for (int kk=0;kk<4;kk++){
      wf[kk*2]   = *(const bf16x8*)&wdb[((kk*8+wv  )*64+lane)*8];
      wf[kk*2+1] = *(const bf16x8*)&wdb[((kk*8+wv+4)*64+lane)*8];
    }
    __syncthreads();
    // ---- dense MLP: C[128o x 32p]; acc[r][pt]; rolling 8-deep A-frag pipe ----
    f32x4 acc[2][2]={};
    #pragma unroll
    for (int kc=0;kc<2;kc++){
      #pragma unroll
      for (int kk=0;kk<4;kk++){
        int kt = kc*4+kk;
        bf16x8 a0=wf[kk*2], a1=wf[kk*2+1];
        if (kc==0){                       // reload slot with chunk-1 frag
          wf[kk*2]   = *(const bf16x8*)&wdb[(((4+kk)*8+wv  )*64+lane)*8];
          wf[kk*2+1] = *(const bf16x8*)&wdb[(((4+kk)*8+wv+4)*64+lane)*8];
        }
        bf16x8 b0 = *(const bf16x8*)&Vb[col*264      + kt*32 + quad*8];
        bf16x8 b1 = *(const bf16x8*)&Vb[(16+col)*264 + kt*32 + quad*8];
        acc[0][0]=MFMA16(a0,b0,acc[0][0]); acc[0][1]=MFMA16(a0,b1,acc[0][1]);
        acc[1][0]=MFMA16(a1,b0,acc[1][0]); acc[1][1]=MFMA16(a1,b1,acc[1][1]);
      }
    }
    __syncthreads();                       // Vb dead -> Bc
    if (t<128) Bc[t*3] = 0;                // only unwritten im2col slot: x=0,tap0 (o=t)
    // ---- epilogue 1: bn+gelu+max_k, scatter S[o][p] -> im2col Bc[x][o*3+tap] ----
    #pragma unroll
    for (int r=0;r<2;r++){
      #pragma unroll
      for (int pt=0;pt<2;pt++){
        #pragma unroll
        for (int reg=0;reg<4;reg++){
          int o = (wv+r*4)*16 + quad*4 + reg;
          int p = pt*16 + col;
          float val = gelu_f(fmaf(acc[r][pt][reg], Pd[o], Pd[128+o]));
          if (pt==0) val = fmaxf(val, Pd[512+o]);    // p<16: max over k
          u16 bv = f2bf(val);
          if (p&1){
            Bc[((p-1)>>1)*392 + o*3 + 2] = bv;
            if (p<31) Bc[((p+1)>>1)*392 + o*3 + 0] = bv;
          } else {
            Bc[(p>>1)*392 + o*3 + 1] = bv;
          }
        }
      }
    }
    // prefetch conv A-frag chunk0 (kt 0..3 x 2r); latency hides under barrier drain
    bf16x8 cwf[8];
    #pragma unroll
    for (int kk=0;kk<4;kk++){
      cwf[kk*2]   = *(const bf16x8*)&wcb[((kk*8+wv  )*64+lane)*8];
      cwf[kk*2+1] = *(const bf16x8*)&wcb[((kk*8+wv+4)*64+lane)*8];
    }
    __syncthreads();
    // ---- conv: C[128o x 16x] = Wc[128o x 384k] * Bc[384k x 16x]; rolling pipe ----
    f32x4 cacc[2]={};
    #pragma unroll
    for (int kc=0;kc<3;kc++){
      #pragma unroll
      for (int kk=0;kk<4;kk++){
        int kt = kc*4+kk;
        bf16x8 a0=cwf[kk*2], a1=cwf[kk*2+1];
        if (kc<2){                         // reload slot with next chunk's frag
          cwf[kk*2]   = *(const bf16x8*)&wcb[(((kc*4+4+kk)*8+wv  )*64+lane)*8];
          cwf[kk*2+1] = *(const bf16x8*)&wcb[(((kc*4+4+kk)*8+wv+4)*64+lane)*8];
        }
        bf16x8 cb0 = *(const bf16x8*)&Bc[col*392 + kt*32 + quad*8];
        cacc[0]=MFMA16(a0,cb0,cacc[0]);
        cacc[1]=MFMA16(a1,cb0,cacc[1]);
      }
    }
    #pragma unroll
    for (int r=0;r<2;r++){
      #pragma unroll
      for (int reg=0;reg<4;reg++){
        int o = (wv+r*4)*16 + quad*4 + reg;
        float val = gelu_f(fmaf(cacc[r][reg], Pd[256+o], Pd[384+o]));
        out_dn[(b*128+o)*256 + m*16 + col] = val;
      }
    }
  }
}

extern "C" void kernel_launch(void* const* d_in, const int* in_sizes, int n_in,
                              void* d_out, int out_size, void* d_ws, size_t ws_size,
                              hipStream_t stream) {
  const float* sparse_fea = (const float*)d_in[0];
  const float* dense_fea  = (const float*)d_in[1];
  const float* stk_coor   = (const float*)d_in[2];
  // d_in[3] = n_stk_center (16, hardcoded)
  const float* sp_w  = (const float*)d_in[4];
  const float* sp_b  = (const float*)d_in[5];
  const float* sp_g  = (const float*)d_in[6];
  const float* sp_be = (const float*)d_in[7];
  const float* dn_w  = (const float*)d_in[8];
  const float* dn_b  = (const float*)d_in[9];
  const float* dn_g  = (const float*)d_in[10];
  const float* dn_be = (const float*)d_in[11];
  const float* ds_w  = (const float*)d_in[12];
  const float* ds_b  = (const float*)d_in[13];
  const float* ds_g  = (const float*)d_in[14];
  const float* ds_be = (const float*)d_in[15];

  float* out = (float*)d_out;
  // outputs: sparse [0, 524288) | dense [524288, 4718592) | coor [4718592, 4784128)
  int* fps_idx = (int*)d_ws;                              // [0, 16384) B
  int* nn_idx  = fps_idx + 2048;
  u16* wdb = (u16*)((char*)d_ws + 16384);                 // 64 KB  (8kt x 8ot)
  u16* wcb = (u16*)((char*)d_ws + 81920);                 // 96 KB  (12kt x 8ot)
  u16* wsb = (u16*)((char*)d_ws + 180224);                // 256 KB (16kt x 16ot)

  k_prep<<<960, 256, 0, stream>>>(dn_w, ds_w, sp_w, stk_coor,
                                  wdb, wcb, wsb, fps_idx, nn_idx, out + 4718592);
  k_main<<<2176, 256, 0, stream>>>(sparse_fea, wsb, sp_b, sp_g, sp_be,
                                   dense_fea, wdb, dn_b, dn_g, dn_be,
                                   wcb, ds_b, ds_g, ds_be,
                                   fps_idx, nn_idx, out, out + 524288);
}

// Round 6
// 159.271 us; speedup vs baseline: 1.1627x; 1.0209x over previous
//
#include <hip/hip_runtime.h>

// DownSample (fp32 in/out, bf16 MFMA internals), MI355X gfx950
// Shapes: B=128, n_stk=32, n_stk_pnt=32, COOR=32, m=16, k=2
// outputs: sparse_out [128,256,16] | dense_out [128,128,16,16] | coor_out [128,16,32]
//
// R14: I-fetch round. R13's 8-deep pipelines were silently defeated
// (VGPR stayed 40, k_main flat) and ~70% of per-block wall is unexplained
// by data latency with ALL pipes idle -- symptom set matches a straight-line
// megakernel that streams ~30KB of one-shot code through the I$. Re-roll all
// loops that keep static register indexing (MLP/conv/sparse kt loops, stage
// loops, sparse oh loop; epilogues stay unrolled for static acc indices).
// Same op order -> bit-identical outputs. Natural register allocation.

typedef unsigned short u16;
typedef unsigned int   u32;
typedef __attribute__((ext_vector_type(8))) short bf16x8;   // 4 VGPRs
typedef __attribute__((ext_vector_type(4))) float f32x4;

#define BN_SCALE 0.9999950000374997f   // 1/sqrt(1+1e-5)

__device__ __forceinline__ float gelu_f(float x){
  return 0.5f*x*(1.0f + erff(x*0.70710678118654752f));
}
__device__ __forceinline__ u16 f2bf(float f){
  u32 x = __float_as_uint(f);
  x += 0x7fffu + ((x>>16)&1u);           // RNE
  return (u16)(x>>16);
}
#define MFMA16(a,b,c) __builtin_amdgcn_mfma_f32_16x16x32_bf16(a,b,c,0,0,0)

// ---------------- kernel 1: weight swizzle (blocks 0..831) + FPS (832..959) ----------------
// A-frag layout: afrag[(kt*NT + ot)*64 + lane][j] = W[o = ot*16+(lane&15)][k = kt*32+((lane>>4)&3)*8+j]
__global__ __launch_bounds__(256) void k_prep(
    const float* __restrict__ dn_w, const float* __restrict__ ds_w, const float* __restrict__ sp_w,
    const float* __restrict__ coor,
    u16* __restrict__ wdb, u16* __restrict__ wcb, u16* __restrict__ wsb,
    int* __restrict__ fps_idx, int* __restrict__ nn_idx, float* __restrict__ coor_out)
{
  int blk = blockIdx.x, t = threadIdx.x;
  if (blk < 128){                       // dense MLP W [128o x 256k] -> 8kt x 8ot
    int w = blk*256 + t;
    int j=w&7, lane=(w>>3)&63, tile=w>>9;
    int kt=tile>>3, ot=tile&7;
    int o=ot*16+(lane&15), i=kt*32+((lane>>4)&3)*8+j;
    wdb[w] = f2bf(dn_w[o*256+i]);
  } else if (blk < 320){                // conv W [128o x 384k] -> 12kt x 8ot
    int w = (blk-128)*256 + t;
    int j=w&7, lane=(w>>3)&63, tile=w>>9;
    int kt=tile>>3, ot=tile&7;
    int o=ot*16+(lane&15), k=kt*32+((lane>>4)&3)*8+j;
    wcb[w] = f2bf(ds_w[o*384+k]);
  } else if (blk < 832){                // sparse W [256o x 512k] -> 16kt x 16ot
    int w = (blk-320)*256 + t;
    int j=w&7, lane=(w>>3)&63, tile=w>>9;
    int kt=tile>>4, ot=tile&15;
    int o=ot*16+(lane&15), i=kt*32+((lane>>4)&3)*8+j;
    wsb[w] = f2bf(sp_w[o*512+i]);
  } else {
    // ---- FPS + NN + coor_out for b = blk-832 ----
    int b = blk - 832;
    __shared__ float Xs[32*33];
    __shared__ float D[32*33];
    __shared__ int   s_sel[16];
    for (int i=t;i<1024;i+=256) Xs[(i>>5)*33 + (i&31)] = coor[b*1024+i];
    __syncthreads();
    #pragma unroll
    for (int k2=0;k2<4;k2++){
      int p=t+k2*256, i=p>>5, j=p&31;
      float d=0.f;
      #pragma unroll
      for (int c=0;c<32;c++){ float df=Xs[i*33+c]-Xs[j*33+c]; d+=df*df; }
      D[i*33+j]=d;
    }
    __syncthreads();
    if (t < 64){
      int j = t & 31;
      float dist = 3.0e38f;
      int far = 0;
      #pragma unroll
      for (int it=0; it<16; ++it){
        if (t==0) s_sel[it]=far;
        dist = fminf(dist, D[far*33+j]);
        float v=dist; int idx=j;              // argmax, first-index tie-break
        #pragma unroll
        for (int off=16; off>=1; off>>=1){
          float v2=__shfl_xor(v,off,32); int i2=__shfl_xor(idx,off,32);
          if (v2>v || (v2==v && i2<idx)){ v=v2; idx=i2; }
        }
        far = idx;
      }
      if (t==0){
        #pragma unroll
        for (int it=0;it<16;++it) fps_idx[b*16+it]=s_sel[it];
      }
    }
    __syncthreads();
    {
      int wv=t>>6, j=t&31;
      #pragma unroll
      for (int q=0;q<4;q++){
        int it = wv*4+q, sel = s_sel[it];
        float d = D[sel*33+j];
        if (j==sel) d=3.0e38f;
        float v=d; int idx=j;                 // argmin, first-index tie-break
        #pragma unroll
        for (int off=16; off>=1; off>>=1){
          float v2=__shfl_xor(v,off,32); int i2=__shfl_xor(idx,off,32);
          if (v2<v || (v2==v && i2<idx)){ v=v2; idx=i2; }
        }
        if ((t&63)==0) nn_idx[b*16+it]=idx;
      }
    }
    for (int q=t;q<512;q+=256){
      int mm=q>>5, c=q&31;
      coor_out[b*512+q] = Xs[s_sel[mm]*33 + c];
    }
  }
}

// ---------------- kernel 2: fused sparse (blocks 0..127, 1 b each) + dense (128..2175, 1 m each) ----
__global__ __launch_bounds__(256) void k_main(
    const float* __restrict__ sfea, const u16* __restrict__ wsb,
    const float* __restrict__ sp_b, const float* __restrict__ sp_g, const float* __restrict__ sp_be,
    const float* __restrict__ dfea, const u16* __restrict__ wdb,
    const float* __restrict__ dn_b, const float* __restrict__ dn_g, const float* __restrict__ dn_be,
    const u16* __restrict__ wcb,
    const float* __restrict__ ds_b, const float* __restrict__ ds_g, const float* __restrict__ ds_be,
    const int* __restrict__ fps_idx, const int* __restrict__ nn_idx,
    float* __restrict__ out_sp, float* __restrict__ out_dn)
{
  __shared__ char smem[19456];
  __shared__ int SI[32];
  int blk=blockIdx.x;
  int t=threadIdx.x, lane=t&63, wv=t>>6, quad=lane>>4, col=lane&15;
  if (blk < 128){
    // ======== sparse: b = blk; C = W[256o x 512i] * X[512i x 16m] ========
    int b = blk;
    u16*   Xb = (u16*)smem;                      // [16m][520] u16 = 16640 B
    float* P  = (float*)(smem+16640);            // spA | spB : 512 f32 = 2048 B
    if (t<32){
      SI[t] = ((t<16) ? fps_idx[b*16+t] : nn_idx[b*16+(t-16)]) & 31;
    }
    { float A = sp_g[t]*BN_SCALE; P[t]=A; P[256+t]=fmaf(sp_b[t],A,sp_be[t]); }
    __syncthreads();
    {
      const float* row = sfea + b*8192 + t*32;   // channel t
      #pragma unroll 1
      for (int m=0;m<16;m++){
        float vc=row[SI[m]], vn=row[SI[16+m]];
        Xb[m*520 + t]       = f2bf(vn-vc);   // i<256: diff
        Xb[m*520 + 256 + t] = f2bf(vc);      // i>=256: ctr
      }
    }
    __syncthreads();
    #pragma unroll 1
    for (int oh=0;oh<2;oh++){
      f32x4 accA[2]={}, accB[2]={};              // [r]
      #pragma unroll 1
      for (int kt=0;kt<8;kt++){
        bf16x8 bf0 = *(const bf16x8*)&Xb[col*520 + kt*32 + quad*8];
        bf16x8 a0  = *(const bf16x8*)&wsb[((kt*16 + oh*8 + wv    )*64+lane)*8];
        bf16x8 a1  = *(const bf16x8*)&wsb[((kt*16 + oh*8 + wv + 4)*64+lane)*8];
        accA[0]=MFMA16(a0,bf0,accA[0]); accA[1]=MFMA16(a1,bf0,accA[1]);
      }
      #pragma unroll 1
      for (int kt=8;kt<16;kt++){
        bf16x8 bf0 = *(const bf16x8*)&Xb[col*520 + kt*32 + quad*8];
        bf16x8 a0  = *(const bf16x8*)&wsb[((kt*16 + oh*8 + wv    )*64+lane)*8];
        bf16x8 a1  = *(const bf16x8*)&wsb[((kt*16 + oh*8 + wv + 4)*64+lane)*8];
        accB[0]=MFMA16(a0,bf0,accB[0]); accB[1]=MFMA16(a1,bf0,accB[1]);
      }
      #pragma unroll
      for (int r=0;r<2;r++){
        #pragma unroll
        for (int reg=0;reg<4;reg++){
          int o = oh*128 + (wv+r*4)*16 + quad*4 + reg;
          float A=P[o], Bv=P[256+o];
          float k1 = accA[r][reg]+accB[r][reg];  // k=1: [diff|ctr]
          float k0 = accB[r][reg];               // k=0: diff part exactly 0
          float v = fmaxf(gelu_f(fmaf(k1,A,Bv)), gelu_f(fmaf(k0,A,Bv)));
          out_sp[(b*256+o)*16 + col] = v;
        }
      }
    }
  } else {
    // ======== dense: d=blk-128; b=((d>>7)<<3)|(d&7); m=(d>>3)&15 ========
    int d=blk-128;
    int b = ((d>>7)<<3) | (d&7), m = (d>>3)&15;
    u16* Vb = (u16*)smem;                 // phase 1: [32p][264] bf16 = 16896 B
    u16* Bc = (u16*)smem;                 // phase 2: [16x][392] bf16 = 12544 B
    float* Pd = (float*)(smem+16896);     // dnA|dnB|dsA|dsB|a0 : 640 f32 = 2560 B
    int ci=fps_idx[b*16+m]&31, ni=nn_idx[b*16+m]&31;
    if (t < 128){                         // fold BN: out = gelu(acc*A + B)
      float A  = dn_g[t]*BN_SCALE; float Bv = fmaf(dn_b[t], A, dn_be[t]);
      float Ac = ds_g[t]*BN_SCALE; float Cv = fmaf(ds_b[t], Ac, ds_be[t]);
      Pd[t]=A; Pd[128+t]=Bv; Pd[256+t]=Ac; Pd[384+t]=Cv;
      Pd[512+t]=gelu_f(Bv);               // a0 (k=0 diff value)
    }
    const float* Db = dfea + b*131072;    // dfea[b][c][s][x]: c*1024 + s*32 + x
    #pragma unroll 1
    for (int it=0; it<2; it++){
      int w = t + it*256;                 // 0..511 : cpair(64) x xq(8)
      int c = (w>>3)*2, x = (w&7)*4;
      const float* base = Db + c*1024 + x;
      float4 fcA = *(const float4*)(base + ci*32);
      float4 fnA = *(const float4*)(base + ni*32);
      float4 fcB = *(const float4*)(base + 1024 + ci*32);
      float4 fnB = *(const float4*)(base + 1024 + ni*32);
      #pragma unroll
      for (int e=0;e<4;e++){
        int xx=x+e, dp=xx&1, p=xx>>1;
        u32 dlo = f2bf(((const float*)&fnA)[e] - ((const float*)&fcA)[e]);
        u32 dhi = f2bf(((const float*)&fnB)[e] - ((const float*)&fcB)[e]);
        u32 clo = f2bf(((const float*)&fcA)[e]);
        u32 chi = f2bf(((const float*)&fcB)[e]);
        *(u32*)&Vb[p*264 + dp*128 + c]      = dlo | (dhi<<16);   // diff cols p<16
        *(u32*)&Vb[(16+p)*264 + dp*128 + c] = clo | (chi<<16);   // ctr cols p>=16
      }
    }
    __syncthreads();
    // ---- dense MLP: C[128o x 32p]; acc[r][pt] ----
    f32x4 acc[2][2]={};
    #pragma unroll 1
    for (int kt=0;kt<8;kt++){
      bf16x8 a0 = *(const bf16x8*)&wdb[((kt*8+wv  )*64+lane)*8];
      bf16x8 a1 = *(const bf16x8*)&wdb[((kt*8+wv+4)*64+lane)*8];
      bf16x8 b0 = *(const bf16x8*)&Vb[col*264      + kt*32 + quad*8];
      bf16x8 b1 = *(const bf16x8*)&Vb[(16+col)*264 + kt*32 + quad*8];
      acc[0][0]=MFMA16(a0,b0,acc[0][0]); acc[0][1]=MFMA16(a0,b1,acc[0][1]);
      acc[1][0]=MFMA16(a1,b0,acc[1][0]); acc[1][1]=MFMA16(a1,b1,acc[1][1]);
    }
    __syncthreads();                       // Vb dead -> Bc
    if (t<128) Bc[t*3] = 0;                // only unwritten im2col slot: x=0,tap0 (o=t)
    // ---- epilogue 1: bn+gelu+max_k, scatter S[o][p] -> im2col Bc[x][o*3+tap] ----
    #pragma unroll
    for (int r=0;r<2;r++){
      #pragma unroll
      for (int pt=0;pt<2;pt++){
        #pragma unroll
        for (int reg=0;reg<4;reg++){
          int o = (wv+r*4)*16 + quad*4 + reg;
          int p = pt*16 + col;
          float val = gelu_f(fmaf(acc[r][pt][reg], Pd[o], Pd[128+o]));
          if (pt==0) val = fmaxf(val, Pd[512+o]);    // p<16: max over k
          u16 bv = f2bf(val);
          if (p&1){
            Bc[((p-1)>>1)*392 + o*3 + 2] = bv;
            if (p<31) Bc[((p+1)>>1)*392 + o*3 + 0] = bv;
          } else {
            Bc[(p>>1)*392 + o*3 + 1] = bv;
          }
        }
      }
    }
    __syncthreads();
    // ---- conv: C[128o x 16x] = Wc[128o x 384k] * Bc[384k x 16x] ----
    f32x4 cacc[2]={};
    #pragma unroll 1
    for (int kt=0;kt<12;kt++){
      bf16x8 cb0 = *(const bf16x8*)&Bc[col*392 + kt*32 + quad*8];
      bf16x8 a0  = *(const bf16x8*)&wcb[((kt*8+wv  )*64+lane)*8];
      bf16x8 a1  = *(const bf16x8*)&wcb[((kt*8+wv+4)*64+lane)*8];
      cacc[0]=MFMA16(a0,cb0,cacc[0]);
      cacc[1]=MFMA16(a1,cb0,cacc[1]);
    }
    #pragma unroll
    for (int r=0;r<2;r++){
      #pragma unroll
      for (int reg=0;reg<4;reg++){
        int o = (wv+r*4)*16 + quad*4 + reg;
        float val = gelu_f(fmaf(cacc[r][reg], Pd[256+o], Pd[384+o]));
        out_dn[(b*128+o)*256 + m*16 + col] = val;
      }
    }
  }
}

extern "C" void kernel_launch(void* const* d_in, const int* in_sizes, int n_in,
                              void* d_out, int out_size, void* d_ws, size_t ws_size,
                              hipStream_t stream) {
  const float* sparse_fea = (const float*)d_in[0];
  const float* dense_fea  = (const float*)d_in[1];
  const float* stk_coor   = (const float*)d_in[2];
  // d_in[3] = n_stk_center (16, hardcoded)
  const float* sp_w  = (const float*)d_in[4];
  const float* sp_b  = (const float*)d_in[5];
  const float* sp_g  = (const float*)d_in[6];
  const float* sp_be = (const float*)d_in[7];
  const float* dn_w  = (const float*)d_in[8];
  const float* dn_b  = (const float*)d_in[9];
  const float* dn_g  = (const float*)d_in[10];
  const float* dn_be = (const float*)d_in[11];
  const float* ds_w  = (const float*)d_in[12];
  const float* ds_b  = (const float*)d_in[13];
  const float* ds_g  = (const float*)d_in[14];
  const float* ds_be = (const float*)d_in[15];

  float* out = (float*)d_out;
  // outputs: sparse [0, 524288) | dense [524288, 4718592) | coor [4718592, 4784128)
  int* fps_idx = (int*)d_ws;                              // [0, 16384) B
  int* nn_idx  = fps_idx + 2048;
  u16* wdb = (u16*)((char*)d_ws + 16384);                 // 64 KB  (8kt x 8ot)
  u16* wcb = (u16*)((char*)d_ws + 81920);                 // 96 KB  (12kt x 8ot)
  u16* wsb = (u16*)((char*)d_ws + 180224);                // 256 KB (16kt x 16ot)

  k_prep<<<960, 256, 0, stream>>>(dn_w, ds_w, sp_w, stk_coor,
                                  wdb, wcb, wsb, fps_idx, nn_idx, out + 4718592);
  k_main<<<2176, 256, 0, stream>>>(sparse_fea, wsb, sp_b, sp_g, sp_be,
                                   dense_fea, wdb, dn_b, dn_g, dn_be,
                                   wcb, ds_b, ds_g, ds_be,
                                   fps_idx, nn_idx, out, out + 524288);
}